// Round 1
// baseline (309.496 us; speedup 1.0000x reference)
//
#include <hip/hip_runtime.h>
#include <hip/hip_bf16.h>

typedef short bf16x8 __attribute__((ext_vector_type(8)));
typedef float f32x4 __attribute__((ext_vector_type(4)));

#define N_NODES 1024
#define FDIM 64
#define NG 32   // B * Tp = 2 * 16

// ---------------- K0: pack adjacency into bit mask ----------------
__global__ __launch_bounds__(256) void k_pack(const int* __restrict__ adj,
                                              unsigned* __restrict__ adjw) {
    int w = blockIdx.x * 256 + threadIdx.x;      // 1024*32 = 32768 words
    const int* p = adj + (size_t)w * 32;
    unsigned m = 0;
#pragma unroll
    for (int b = 0; b < 32; b++) m |= (p[b] > 0 ? (1u << b) : 0u);
    adjw[w] = m;
}

// ---------------- K1: layer-1 projection + score vectors ----------------
// h = x @ W[h]  (fp32), f1 = h·a1, f2 = h·a2 ; write H1T bf16 [h][g][f][n]
__global__ __launch_bounds__(256) void k_proj1(const float* __restrict__ x,
                                               const float* __restrict__ Wh,
                                               const float* __restrict__ ah,
                                               __hip_bfloat16* __restrict__ H1T,
                                               float* __restrict__ F1,
                                               float* __restrict__ F2) {
    __shared__ float xs[64][68];
    __shared__ float ws[64][64];
    const int t = threadIdx.x;
    const int nt = blockIdx.x, g = blockIdx.y, h = blockIdx.z;
    const int n0 = nt * 64;
    const int b = g >> 4, tstep = g & 15;
    const int r = t >> 2, cq = t & 3;

    // stage x tile [64 n][64 f]
    const float* xrow = x + (((size_t)(b * 17 + tstep) * N_NODES + n0 + r) * FDIM);
    const float4* xsrc = (const float4*)(xrow + cq * 16);
#pragma unroll
    for (int q = 0; q < 4; q++) *(float4*)&xs[r][cq * 16 + q * 4] = xsrc[q];
    // stage W[h] tile [64 k][64 o]
    const float4* wsrc = (const float4*)(Wh + (size_t)h * 4096 + (size_t)r * 64 + cq * 16);
#pragma unroll
    for (int q = 0; q < 4; q++) *(float4*)&ws[r][cq * 16 + q * 4] = wsrc[q];
    __syncthreads();

    float acc[16];
#pragma unroll
    for (int c = 0; c < 16; c++) acc[c] = 0.f;
    for (int k = 0; k < 64; k++) {
        float a = xs[r][k];
        const float* wr = &ws[k][cq * 16];
#pragma unroll
        for (int c = 0; c < 16; c++) acc[c] = fmaf(a, wr[c], acc[c]);
    }

    // score partials
    const float* a1 = ah + h * 128;
    float p1 = 0.f, p2 = 0.f;
#pragma unroll
    for (int c = 0; c < 16; c++) {
        p1 = fmaf(acc[c], a1[cq * 16 + c], p1);
        p2 = fmaf(acc[c], a1[64 + cq * 16 + c], p2);
    }
    p1 += __shfl_xor(p1, 1); p1 += __shfl_xor(p1, 2);
    p2 += __shfl_xor(p2, 1); p2 += __shfl_xor(p2, 2);
    const int n = n0 + r;
    const size_t gh = (size_t)h * NG + g;
    if (cq == 0) {
        F1[gh * N_NODES + n] = p1;
        F2[gh * N_NODES + n] = p2;
    }
    // H1T bf16 transposed [f][n]
    __hip_bfloat16* Hb = H1T + gh * FDIM * N_NODES;
#pragma unroll
    for (int c = 0; c < 16; c++)
        Hb[(size_t)(cq * 16 + c) * N_NODES + n] = __float2bfloat16(acc[c]);
}

// ---------------- K2: layer-1 fused masked attention + ELU ----------------
// per block: 64 output rows for one (g,h); 4 waves x 16 rows; PV via MFMA
__global__ __launch_bounds__(256) void k_attn1(const __hip_bfloat16* __restrict__ H1T,
                                               const float* __restrict__ F1,
                                               const float* __restrict__ F2,
                                               const unsigned* __restrict__ adjw,
                                               __hip_bfloat16* __restrict__ HC) {
    __shared__ __hip_bfloat16 vt[64][40];   // [f][j] tile, padded
    __shared__ unsigned mk[64][33];         // mask words for 64 rows, padded
    __shared__ float f2s[N_NODES];
    __shared__ float f1s[64];
    __shared__ float rsm[64];
    const int t = threadIdx.x;
    const int nt = blockIdx.x, g = blockIdx.y, h = blockIdx.z;
    const int i0 = nt * 64;
    const size_t gh = (size_t)h * NG + g;

    ((float4*)f2s)[t] = ((const float4*)(F2 + gh * N_NODES))[t];
    if (t < 64) f1s[t] = F1[gh * N_NODES + i0 + t];
#pragma unroll
    for (int q = 0; q < 8; q++) {
        int idx = t * 8 + q, row = idx >> 5, w = idx & 31;
        mk[row][w] = adjw[(size_t)(i0 + row) * 32 + w];
    }
    __syncthreads();

    const int wave = t >> 6, lane = t & 63;
    const int li = lane & 15, grp = lane >> 4;
    const int il = wave * 16 + li;
    const float f1v = f1s[il];
    const int jb = grp * 8;

    f32x4 acc[4];
#pragma unroll
    for (int q = 0; q < 4; q++) acc[q] = (f32x4){0.f, 0.f, 0.f, 0.f};
    float rsum = 0.f;
    const __hip_bfloat16* Hg = H1T + gh * FDIM * N_NODES;
    const int sr = t >> 2, sq = t & 3;

    for (int j0 = 0; j0 < N_NODES; j0 += 32) {
        // stage V tile [64 f][32 j]
        bf16x8 sv = *(const bf16x8*)(Hg + (size_t)sr * N_NODES + j0 + sq * 8);
        *(bf16x8*)&vt[sr][sq * 8] = sv;
        __syncthreads();

        unsigned mw = mk[il][j0 >> 5];
        float4 fa = *(const float4*)&f2s[j0 + jb];
        float4 fb = *(const float4*)&f2s[j0 + jb + 4];
        float f2arr[8] = {fa.x, fa.y, fa.z, fa.w, fb.x, fb.y, fb.z, fb.w};
        union { bf16x8 v; __hip_bfloat16 hh[8]; } afr;
#pragma unroll
        for (int c = 0; c < 8; c++) {
            float s = f1v + f2arr[c];
            s = s > 0.f ? s : 0.2f * s;
            float p = ((mw >> (jb + c)) & 1u) ? __expf(s) : 0.f;
            rsum += p;
            afr.hh[c] = __float2bfloat16(p);
        }
#pragma unroll
        for (int q = 0; q < 4; q++) {
            bf16x8 bfr = *(const bf16x8*)&vt[q * 16 + li][jb];
            acc[q] = __builtin_amdgcn_mfma_f32_16x16x32_bf16(afr.v, bfr, acc[q], 0, 0, 0);
        }
        __syncthreads();
    }

    rsum += __shfl_xor(rsum, 16);
    rsum += __shfl_xor(rsum, 32);
    if (grp == 0) rsm[il] = rsum;
    __syncthreads();

    // epilogue: normalize, ELU, write concat slice (bf16)
    __hip_bfloat16* HCg = HC + (size_t)g * N_NODES * 256 + h * 64;
#pragma unroll
    for (int q = 0; q < 4; q++) {
#pragma unroll
        for (int r2 = 0; r2 < 4; r2++) {
            int irow = wave * 16 + grp * 4 + r2;
            float v = acc[q][r2] / rsm[irow];
            v = v > 0.f ? v : expm1f(v);
            HCg[(size_t)(i0 + irow) * 256 + q * 16 + li] = __float2bfloat16(v);
        }
    }
}

// ---------------- K3: layer-2 projection + score vectors ----------------
__global__ __launch_bounds__(256) void k_proj2(const __hip_bfloat16* __restrict__ HC,
                                               const float* __restrict__ Wo,
                                               const float* __restrict__ ao,
                                               __hip_bfloat16* __restrict__ H2T,
                                               float* __restrict__ F1b,
                                               float* __restrict__ F2b) {
    __shared__ float xs[64][68];
    __shared__ float ws[64][64];
    const int t = threadIdx.x;
    const int nt = blockIdx.x, g = blockIdx.y;
    const int n0 = nt * 64;
    const int r = t >> 2, cq = t & 3;
    float acc[16];
#pragma unroll
    for (int c = 0; c < 16; c++) acc[c] = 0.f;

    for (int k0 = 0; k0 < 256; k0 += 64) {
        const __hip_bfloat16* src = HC + ((size_t)g * N_NODES + n0 + r) * 256 + k0 + cq * 16;
        union { bf16x8 v; __hip_bfloat16 hh[8]; } u0, u1;
        u0.v = *(const bf16x8*)(src);
        u1.v = *(const bf16x8*)(src + 8);
#pragma unroll
        for (int c = 0; c < 8; c++) {
            xs[r][cq * 16 + c] = __bfloat162float(u0.hh[c]);
            xs[r][cq * 16 + 8 + c] = __bfloat162float(u1.hh[c]);
        }
        const float4* wsrc = (const float4*)(Wo + (size_t)(k0 + r) * 64 + cq * 16);
#pragma unroll
        for (int q = 0; q < 4; q++) *(float4*)&ws[r][cq * 16 + q * 4] = wsrc[q];
        __syncthreads();
        for (int k = 0; k < 64; k++) {
            float a = xs[r][k];
            const float* wr = &ws[k][cq * 16];
#pragma unroll
            for (int c = 0; c < 16; c++) acc[c] = fmaf(a, wr[c], acc[c]);
        }
        __syncthreads();
    }

    float p1 = 0.f, p2 = 0.f;
#pragma unroll
    for (int c = 0; c < 16; c++) {
        p1 = fmaf(acc[c], ao[cq * 16 + c], p1);
        p2 = fmaf(acc[c], ao[64 + cq * 16 + c], p2);
    }
    p1 += __shfl_xor(p1, 1); p1 += __shfl_xor(p1, 2);
    p2 += __shfl_xor(p2, 1); p2 += __shfl_xor(p2, 2);
    const int n = n0 + r;
    if (cq == 0) {
        F1b[(size_t)g * N_NODES + n] = p1;
        F2b[(size_t)g * N_NODES + n] = p2;
    }
    __hip_bfloat16* Hb = H2T + (size_t)g * FDIM * N_NODES;
#pragma unroll
    for (int c = 0; c < 16; c++)
        Hb[(size_t)(cq * 16 + c) * N_NODES + n] = __float2bfloat16(acc[c]);
}

// ---------------- K4: layer-2 fused masked attention + ReLU ----------------
__global__ __launch_bounds__(256) void k_attn2(const __hip_bfloat16* __restrict__ H2T,
                                               const float* __restrict__ F1b,
                                               const float* __restrict__ F2b,
                                               const unsigned* __restrict__ adjw,
                                               float* __restrict__ out) {
    __shared__ __hip_bfloat16 vt[64][40];
    __shared__ unsigned mk[64][33];
    __shared__ float f2s[N_NODES];
    __shared__ float f1s[64];
    __shared__ float rsm[64];
    const int t = threadIdx.x;
    const int nt = blockIdx.x, g = blockIdx.y;
    const int i0 = nt * 64;

    ((float4*)f2s)[t] = ((const float4*)(F2b + (size_t)g * N_NODES))[t];
    if (t < 64) f1s[t] = F1b[(size_t)g * N_NODES + i0 + t];
#pragma unroll
    for (int q = 0; q < 8; q++) {
        int idx = t * 8 + q, row = idx >> 5, w = idx & 31;
        mk[row][w] = adjw[(size_t)(i0 + row) * 32 + w];
    }
    __syncthreads();

    const int wave = t >> 6, lane = t & 63;
    const int li = lane & 15, grp = lane >> 4;
    const int il = wave * 16 + li;
    const float f1v = f1s[il];
    const int jb = grp * 8;

    f32x4 acc[4];
#pragma unroll
    for (int q = 0; q < 4; q++) acc[q] = (f32x4){0.f, 0.f, 0.f, 0.f};
    float rsum = 0.f;
    const __hip_bfloat16* Hg = H2T + (size_t)g * FDIM * N_NODES;
    const int sr = t >> 2, sq = t & 3;

    for (int j0 = 0; j0 < N_NODES; j0 += 32) {
        bf16x8 sv = *(const bf16x8*)(Hg + (size_t)sr * N_NODES + j0 + sq * 8);
        *(bf16x8*)&vt[sr][sq * 8] = sv;
        __syncthreads();

        unsigned mw = mk[il][j0 >> 5];
        float4 fa = *(const float4*)&f2s[j0 + jb];
        float4 fb = *(const float4*)&f2s[j0 + jb + 4];
        float f2arr[8] = {fa.x, fa.y, fa.z, fa.w, fb.x, fb.y, fb.z, fb.w};
        union { bf16x8 v; __hip_bfloat16 hh[8]; } afr;
#pragma unroll
        for (int c = 0; c < 8; c++) {
            float s = f1v + f2arr[c];
            s = s > 0.f ? s : 0.2f * s;
            float p = ((mw >> (jb + c)) & 1u) ? __expf(s) : 0.f;
            rsum += p;
            afr.hh[c] = __float2bfloat16(p);
        }
#pragma unroll
        for (int q = 0; q < 4; q++) {
            bf16x8 bfr = *(const bf16x8*)&vt[q * 16 + li][jb];
            acc[q] = __builtin_amdgcn_mfma_f32_16x16x32_bf16(afr.v, bfr, acc[q], 0, 0, 0);
        }
        __syncthreads();
    }

    rsum += __shfl_xor(rsum, 16);
    rsum += __shfl_xor(rsum, 32);
    if (grp == 0) rsm[il] = rsum;
    __syncthreads();

    float* og = out + (size_t)g * N_NODES * FDIM;
#pragma unroll
    for (int q = 0; q < 4; q++) {
#pragma unroll
        for (int r2 = 0; r2 < 4; r2++) {
            int irow = wave * 16 + grp * 4 + r2;
            float v = acc[q][r2] / rsm[irow];
            og[(size_t)(i0 + irow) * FDIM + q * 16 + li] = v > 0.f ? v : 0.f;
        }
    }
}

extern "C" void kernel_launch(void* const* d_in, const int* in_sizes, int n_in,
                              void* d_out, int out_size, void* d_ws, size_t ws_size,
                              hipStream_t stream) {
    const float* x  = (const float*)d_in[0];
    const int* adj  = (const int*)d_in[1];
    const float* Wh = (const float*)d_in[2];
    const float* ah = (const float*)d_in[3];
    const float* Wo = (const float*)d_in[4];
    const float* ao = (const float*)d_in[5];

    char* ws = (char*)d_ws;
    unsigned* adjw = (unsigned*)(ws);                       // 131072 B
    float* F1  = (float*)(ws + 131072);                     // 524288 B
    float* F2  = (float*)(ws + 655360);                     // 524288 B
    float* F1b = (float*)(ws + 1179648);                    // 131072 B
    float* F2b = (float*)(ws + 1310720);                    // 131072 B
    __hip_bfloat16* H1T = (__hip_bfloat16*)(ws + 1441792);            // 16 MB
    __hip_bfloat16* HC  = (__hip_bfloat16*)(ws + 1441792 + 16777216); // 16 MB
    __hip_bfloat16* H2T = (__hip_bfloat16*)(ws + 1441792 + 33554432); //  4 MB
    float* out = (float*)d_out;

    k_pack <<<dim3(128),        dim3(256), 0, stream>>>(adj, adjw);
    k_proj1<<<dim3(16, 32, 4),  dim3(256), 0, stream>>>(x, Wh, ah, H1T, F1, F2);
    k_attn1<<<dim3(16, 32, 4),  dim3(256), 0, stream>>>(H1T, F1, F2, adjw, HC);
    k_proj2<<<dim3(16, 32),     dim3(256), 0, stream>>>(HC, Wo, ao, H2T, F1b, F2b);
    k_attn2<<<dim3(16, 32),     dim3(256), 0, stream>>>(H2T, F1b, F2b, adjw, out);
}

// Round 2
// 131.664 us; speedup vs baseline: 2.3507x; 2.3507x over previous
//
#include <hip/hip_runtime.h>
#include <hip/hip_bf16.h>

typedef short bf16x8 __attribute__((ext_vector_type(8)));
typedef float f32x4 __attribute__((ext_vector_type(4)));

#define N_NODES 1024
#define FDIM 64
#define NG 32   // B * Tp = 2 * 16

// ---------------- K0: pack adjacency into bit mask ----------------
__global__ __launch_bounds__(256) void k_pack(const int* __restrict__ adj,
                                              unsigned* __restrict__ adjw) {
    int w = blockIdx.x * 256 + threadIdx.x;      // 1024*32 = 32768 words
    const int* p = adj + (size_t)w * 32;
    unsigned m = 0;
#pragma unroll
    for (int b = 0; b < 32; b++) m |= (p[b] > 0 ? (1u << b) : 0u);
    adjw[w] = m;
}

// ---------------- K1: layer-1 projection + score vectors ----------------
__global__ __launch_bounds__(256) void k_proj1(const float* __restrict__ x,
                                               const float* __restrict__ Wh,
                                               const float* __restrict__ ah,
                                               __hip_bfloat16* __restrict__ H1T,
                                               float* __restrict__ F1,
                                               float* __restrict__ F2) {
    __shared__ float xs[64][68];
    __shared__ float ws[64][64];
    const int t = threadIdx.x;
    const int nt = blockIdx.x, g = blockIdx.y, h = blockIdx.z;
    const int n0 = nt * 64;
    const int b = g >> 4, tstep = g & 15;
    const int r = t >> 2, cq = t & 3;

    const float* xrow = x + (((size_t)(b * 17 + tstep) * N_NODES + n0 + r) * FDIM);
    const float4* xsrc = (const float4*)(xrow + cq * 16);
#pragma unroll
    for (int q = 0; q < 4; q++) *(float4*)&xs[r][cq * 16 + q * 4] = xsrc[q];
    const float4* wsrc = (const float4*)(Wh + (size_t)h * 4096 + (size_t)r * 64 + cq * 16);
#pragma unroll
    for (int q = 0; q < 4; q++) *(float4*)&ws[r][cq * 16 + q * 4] = wsrc[q];
    __syncthreads();

    float acc[16];
#pragma unroll
    for (int c = 0; c < 16; c++) acc[c] = 0.f;
    for (int k = 0; k < 64; k++) {
        float a = xs[r][k];
        const float* wr = &ws[k][cq * 16];
#pragma unroll
        for (int c = 0; c < 16; c++) acc[c] = fmaf(a, wr[c], acc[c]);
    }

    const float* a1 = ah + h * 128;
    float p1 = 0.f, p2 = 0.f;
#pragma unroll
    for (int c = 0; c < 16; c++) {
        p1 = fmaf(acc[c], a1[cq * 16 + c], p1);
        p2 = fmaf(acc[c], a1[64 + cq * 16 + c], p2);
    }
    p1 += __shfl_xor(p1, 1); p1 += __shfl_xor(p1, 2);
    p2 += __shfl_xor(p2, 1); p2 += __shfl_xor(p2, 2);
    const int n = n0 + r;
    const size_t gh = (size_t)h * NG + g;
    if (cq == 0) {
        F1[gh * N_NODES + n] = p1;
        F2[gh * N_NODES + n] = p2;
    }
    __hip_bfloat16* Hb = H1T + gh * FDIM * N_NODES;
#pragma unroll
    for (int c = 0; c < 16; c++)
        Hb[(size_t)(cq * 16 + c) * N_NODES + n] = __float2bfloat16(acc[c]);
}

// ---------------- fused masked attention template ----------------
// 128 output rows / block, 8 waves x 16 rows; j-tile = 256 staged in LDS
// (padded, conflict-balanced); T14 reg-staging prefetch; PV via bf16 MFMA.
template<int CONCAT>
__global__ __launch_bounds__(512, 4) void k_attn(
    const __hip_bfloat16* __restrict__ HT,   // [G][64 f][1024 n] bf16
    const float* __restrict__ F1,            // [G][1024]
    const float* __restrict__ F2,            // [G][1024]
    const unsigned* __restrict__ adjw,       // [1024][32]
    __hip_bfloat16* __restrict__ HC,         // concat out (CONCAT=1)
    float* __restrict__ out)                 // final out (CONCAT=0)
{
    __shared__ __hip_bfloat16 vt[64][264];   // 528B row stride: balanced b128
    __shared__ unsigned mk[128][33];         // padded: conflict-free
    __shared__ float f2s[N_NODES];
    const int t = threadIdx.x;
    const int nb = blockIdx.x, g = blockIdx.y, h = blockIdx.z;
    const int i0 = nb * 128;
    const size_t gidx = CONCAT ? ((size_t)h * NG + g) : (size_t)g;

    ((float2*)f2s)[t] = ((const float2*)(F2 + gidx * N_NODES))[t];
#pragma unroll
    for (int q = 0; q < 8; q++) {
        int idx = q * 512 + t;
        mk[idx >> 5][idx & 31] = adjw[((size_t)(i0 + (idx >> 5))) * 32 + (idx & 31)];
    }

    const int wv = t >> 6, ln = t & 63;
    const int li = ln & 15, grp = ln >> 4, jb = grp * 8;
    const int il = wv * 16 + li;
    const float f1v = F1[gidx * N_NODES + i0 + il];

    const __hip_bfloat16* Hg = HT + gidx * (size_t)(FDIM * N_NODES);
    const int srow = wv * 8 + (ln >> 3);     // staging row (f)
    const int scol = (ln & 7) * 32;          // staging col (j el in tile)
    const __hip_bfloat16* srcb = Hg + (size_t)srow * N_NODES + scol;

    f32x4 acc[4];
#pragma unroll
    for (int q = 0; q < 4; q++) acc[q] = (f32x4){0.f, 0.f, 0.f, 0.f};
    float rsum = 0.f;

    bf16x8 stg[4];
#pragma unroll
    for (int k2 = 0; k2 < 4; k2++) stg[k2] = *(const bf16x8*)(srcb + k2 * 8);

    for (int jt = 0; jt < 4; jt++) {
        __syncthreads();                     // prev compute done; vt free
#pragma unroll
        for (int k2 = 0; k2 < 4; k2++) *(bf16x8*)&vt[srow][scol + k2 * 8] = stg[k2];
        if (jt < 3) {                        // prefetch next tile under compute
#pragma unroll
            for (int k2 = 0; k2 < 4; k2++)
                stg[k2] = *(const bf16x8*)(srcb + (jt + 1) * 256 + k2 * 8);
        }
        __syncthreads();

        const int jw0 = jt * 8;
#pragma unroll
        for (int jc = 0; jc < 8; jc++) {
            unsigned mw = mk[il][jw0 + jc];
            const float* f2p = &f2s[jt * 256 + jc * 32 + jb];
            float4 fa = *(const float4*)f2p;
            float4 fb = *(const float4*)(f2p + 4);
            float f2a[8] = {fa.x, fa.y, fa.z, fa.w, fb.x, fb.y, fb.z, fb.w};
            union { bf16x8 v; __hip_bfloat16 hh[8]; } afr;
#pragma unroll
            for (int c = 0; c < 8; c++) {
                float s = f1v + f2a[c];
                s = fmaxf(s, 0.2f * s);      // LeakyReLU(0.2)
                float p = ((mw >> (jb + c)) & 1u) ? __expf(s) : 0.f;
                rsum += p;
                afr.hh[c] = __float2bfloat16(p);
            }
#pragma unroll
            for (int q = 0; q < 4; q++) {
                bf16x8 bfr = *(const bf16x8*)&vt[q * 16 + li][jc * 32 + jb];
                acc[q] = __builtin_amdgcn_mfma_f32_16x16x32_bf16(afr.v, bfr, acc[q], 0, 0, 0);
            }
        }
    }

    rsum += __shfl_xor(rsum, 16);
    rsum += __shfl_xor(rsum, 32);
    float rin[4];
#pragma unroll
    for (int r2 = 0; r2 < 4; r2++) rin[r2] = 1.0f / __shfl(rsum, grp * 4 + r2);

    if (CONCAT) {
        __hip_bfloat16* HCg = HC + (size_t)g * N_NODES * 256 + h * 64;
#pragma unroll
        for (int q = 0; q < 4; q++)
#pragma unroll
            for (int r2 = 0; r2 < 4; r2++) {
                int irow = wv * 16 + grp * 4 + r2;
                float v = acc[q][r2] * rin[r2];
                v = v > 0.f ? v : expm1f(v); // ELU
                HCg[(size_t)(i0 + irow) * 256 + q * 16 + li] = __float2bfloat16(v);
            }
    } else {
        float* og = out + (size_t)g * N_NODES * FDIM;
#pragma unroll
        for (int q = 0; q < 4; q++)
#pragma unroll
            for (int r2 = 0; r2 < 4; r2++) {
                int irow = wv * 16 + grp * 4 + r2;
                float v = acc[q][r2] * rin[r2];
                og[(size_t)(i0 + irow) * FDIM + q * 16 + li] = v > 0.f ? v : 0.f;
            }
    }
}

// ---------------- K3: layer-2 projection + score vectors ----------------
__global__ __launch_bounds__(256) void k_proj2(const __hip_bfloat16* __restrict__ HC,
                                               const float* __restrict__ Wo,
                                               const float* __restrict__ ao,
                                               __hip_bfloat16* __restrict__ H2T,
                                               float* __restrict__ F1b,
                                               float* __restrict__ F2b) {
    __shared__ float xs[64][68];
    __shared__ float ws[64][64];
    const int t = threadIdx.x;
    const int nt = blockIdx.x, g = blockIdx.y;
    const int n0 = nt * 64;
    const int r = t >> 2, cq = t & 3;
    float acc[16];
#pragma unroll
    for (int c = 0; c < 16; c++) acc[c] = 0.f;

    for (int k0 = 0; k0 < 256; k0 += 64) {
        const __hip_bfloat16* src = HC + ((size_t)g * N_NODES + n0 + r) * 256 + k0 + cq * 16;
        union { bf16x8 v; __hip_bfloat16 hh[8]; } u0, u1;
        u0.v = *(const bf16x8*)(src);
        u1.v = *(const bf16x8*)(src + 8);
#pragma unroll
        for (int c = 0; c < 8; c++) {
            xs[r][cq * 16 + c] = __bfloat162float(u0.hh[c]);
            xs[r][cq * 16 + 8 + c] = __bfloat162float(u1.hh[c]);
        }
        const float4* wsrc = (const float4*)(Wo + (size_t)(k0 + r) * 64 + cq * 16);
#pragma unroll
        for (int q = 0; q < 4; q++) *(float4*)&ws[r][cq * 16 + q * 4] = wsrc[q];
        __syncthreads();
        for (int k = 0; k < 64; k++) {
            float a = xs[r][k];
            const float* wr = &ws[k][cq * 16];
#pragma unroll
            for (int c = 0; c < 16; c++) acc[c] = fmaf(a, wr[c], acc[c]);
        }
        __syncthreads();
    }

    float p1 = 0.f, p2 = 0.f;
#pragma unroll
    for (int c = 0; c < 16; c++) {
        p1 = fmaf(acc[c], ao[cq * 16 + c], p1);
        p2 = fmaf(acc[c], ao[64 + cq * 16 + c], p2);
    }
    p1 += __shfl_xor(p1, 1); p1 += __shfl_xor(p1, 2);
    p2 += __shfl_xor(p2, 1); p2 += __shfl_xor(p2, 2);
    const int n = n0 + r;
    if (cq == 0) {
        F1b[(size_t)g * N_NODES + n] = p1;
        F2b[(size_t)g * N_NODES + n] = p2;
    }
    __hip_bfloat16* Hb = H2T + (size_t)g * FDIM * N_NODES;
#pragma unroll
    for (int c = 0; c < 16; c++)
        Hb[(size_t)(cq * 16 + c) * N_NODES + n] = __float2bfloat16(acc[c]);
}

extern "C" void kernel_launch(void* const* d_in, const int* in_sizes, int n_in,
                              void* d_out, int out_size, void* d_ws, size_t ws_size,
                              hipStream_t stream) {
    const float* x  = (const float*)d_in[0];
    const int* adj  = (const int*)d_in[1];
    const float* Wh = (const float*)d_in[2];
    const float* ah = (const float*)d_in[3];
    const float* Wo = (const float*)d_in[4];
    const float* ao = (const float*)d_in[5];

    char* ws = (char*)d_ws;
    unsigned* adjw = (unsigned*)(ws);                       // 131072 B
    float* F1  = (float*)(ws + 131072);                     // 524288 B
    float* F2  = (float*)(ws + 655360);                     // 524288 B
    float* F1b = (float*)(ws + 1179648);                    // 131072 B
    float* F2b = (float*)(ws + 1310720);                    // 131072 B
    __hip_bfloat16* H1T = (__hip_bfloat16*)(ws + 1441792);            // 16 MB
    __hip_bfloat16* HC  = (__hip_bfloat16*)(ws + 1441792 + 16777216); // 16 MB
    __hip_bfloat16* H2T = (__hip_bfloat16*)(ws + 1441792 + 33554432); //  4 MB
    float* out = (float*)d_out;

    k_pack   <<<dim3(128),       dim3(256), 0, stream>>>(adj, adjw);
    k_proj1  <<<dim3(16, 32, 4), dim3(256), 0, stream>>>(x, Wh, ah, H1T, F1, F2);
    k_attn<1><<<dim3(8, 32, 4),  dim3(512), 0, stream>>>(H1T, F1, F2, adjw, HC, nullptr);
    k_proj2  <<<dim3(16, 32),    dim3(256), 0, stream>>>(HC, Wo, ao, H2T, F1b, F2b);
    k_attn<0><<<dim3(8, 32, 1),  dim3(512), 0, stream>>>(H2T, F1b, F2b, adjw, nullptr, out);
}

// Round 3
// 126.580 us; speedup vs baseline: 2.4451x; 1.0402x over previous
//
#include <hip/hip_runtime.h>
#include <hip/hip_bf16.h>

typedef short bf16x8 __attribute__((ext_vector_type(8)));
typedef float f32x4 __attribute__((ext_vector_type(4)));

#define N_NODES 1024
#define FDIM 64
#define NG 32   // B * Tp = 2 * 16
#define LOG2E 1.44269504088896f

// ---------------- K0: expand adjacency into additive bf16 mask ----------------
// Madd[i][j] = adj ? 0 : -2048  (exp2 of (score-2048)*0.2 flushes to exactly 0)
__global__ __launch_bounds__(256) void k_maskf(const int* __restrict__ adj,
                                               __hip_bfloat16* __restrict__ Madd) {
    int w = blockIdx.x * 256 + threadIdx.x;      // 32768 threads, 32 els each
    const int* p = adj + (size_t)w * 32;
    union { bf16x8 v[4]; __hip_bfloat16 hh[32]; } u;
#pragma unroll
    for (int b = 0; b < 32; b++)
        u.hh[b] = __float2bfloat16(p[b] > 0 ? 0.f : -2048.f);
    bf16x8* dst = (bf16x8*)(Madd + (size_t)w * 32);
#pragma unroll
    for (int q = 0; q < 4; q++) dst[q] = u.v[q];
}

// ---------------- K1: layer-1 projection + score vectors (pre-scaled by log2e) ----------------
__global__ __launch_bounds__(256) void k_proj1(const float* __restrict__ x,
                                               const float* __restrict__ Wh,
                                               const float* __restrict__ ah,
                                               __hip_bfloat16* __restrict__ H1T,
                                               float* __restrict__ F1,
                                               float* __restrict__ F2) {
    __shared__ float xs[64][68];
    __shared__ float ws[64][64];
    const int t = threadIdx.x;
    const int nt = blockIdx.x, g = blockIdx.y, h = blockIdx.z;
    const int n0 = nt * 64;
    const int b = g >> 4, tstep = g & 15;
    const int r = t >> 2, cq = t & 3;

    const float* xrow = x + (((size_t)(b * 17 + tstep) * N_NODES + n0 + r) * FDIM);
    const float4* xsrc = (const float4*)(xrow + cq * 16);
#pragma unroll
    for (int q = 0; q < 4; q++) *(float4*)&xs[r][cq * 16 + q * 4] = xsrc[q];
    const float4* wsrc = (const float4*)(Wh + (size_t)h * 4096 + (size_t)r * 64 + cq * 16);
#pragma unroll
    for (int q = 0; q < 4; q++) *(float4*)&ws[r][cq * 16 + q * 4] = wsrc[q];
    __syncthreads();

    float acc[16];
#pragma unroll
    for (int c = 0; c < 16; c++) acc[c] = 0.f;
    for (int k = 0; k < 64; k++) {
        float a = xs[r][k];
        const float* wr = &ws[k][cq * 16];
#pragma unroll
        for (int c = 0; c < 16; c++) acc[c] = fmaf(a, wr[c], acc[c]);
    }

    const float* a1 = ah + h * 128;
    float p1 = 0.f, p2 = 0.f;
#pragma unroll
    for (int c = 0; c < 16; c++) {
        p1 = fmaf(acc[c], a1[cq * 16 + c], p1);
        p2 = fmaf(acc[c], a1[64 + cq * 16 + c], p2);
    }
    p1 += __shfl_xor(p1, 1); p1 += __shfl_xor(p1, 2);
    p2 += __shfl_xor(p2, 1); p2 += __shfl_xor(p2, 2);
    const int n = n0 + r;
    const size_t gh = (size_t)h * NG + g;
    if (cq == 0) {
        F1[gh * N_NODES + n] = p1 * LOG2E;
        F2[gh * N_NODES + n] = p2 * LOG2E;
    }
    __hip_bfloat16* Hb = H1T + gh * FDIM * N_NODES;
#pragma unroll
    for (int c = 0; c < 16; c++)
        Hb[(size_t)(cq * 16 + c) * N_NODES + n] = __float2bfloat16(acc[c]);
}

// ---------------- fused masked attention ----------------
// 128 rows/block, 8 waves x 16 rows, j-tile 256 in LDS (conflict-free staging),
// additive-mask + exp2 score path, row-sum via ones-MFMA.
template<int CONCAT>
__global__ __launch_bounds__(512, 6) void k_attn(
    const __hip_bfloat16* __restrict__ HT,   // [G][64 f][1024 n] bf16
    const float* __restrict__ F1,            // [G][1024] (×log2e)
    const float* __restrict__ F2,
    const __hip_bfloat16* __restrict__ Madd, // [1024][1024] additive mask
    __hip_bfloat16* __restrict__ HC,         // concat out (CONCAT=1)
    float* __restrict__ out)                 // final out (CONCAT=0)
{
    __shared__ __hip_bfloat16 vt[64][264];   // 528B row stride
    __shared__ float f2s[N_NODES];
    const int t = threadIdx.x;
    const int nb = blockIdx.x, g = blockIdx.y, h = blockIdx.z;
    const int i0 = nb * 128;
    const size_t gidx = CONCAT ? ((size_t)h * NG + g) : (size_t)g;

    ((float2*)f2s)[t] = ((const float2*)(F2 + gidx * N_NODES))[t];

    const int wv = t >> 6, ln = t & 63;
    const int li = ln & 15, grp = ln >> 4, jb = grp * 8;
    const int il = wv * 16 + li;
    const float f1v = F1[gidx * N_NODES + i0 + il];

    const __hip_bfloat16* Hg = HT + gidx * (size_t)(FDIM * N_NODES);
    const int srow = wv * 8 + (ln >> 3);          // staging row (f)
    const int scol = (ln & 7) * 8;                // 8-lane group: 8 distinct clusters
    const __hip_bfloat16* srcb = Hg + (size_t)srow * N_NODES + scol;
    const __hip_bfloat16* Mrow = Madd + (size_t)(i0 + il) * N_NODES + jb;

    f32x4 acc[4], acc5;
#pragma unroll
    for (int q = 0; q < 4; q++) acc[q] = (f32x4){0.f, 0.f, 0.f, 0.f};
    acc5 = (f32x4){0.f, 0.f, 0.f, 0.f};

    union { bf16x8 v; short s[8]; } onesu;
#pragma unroll
    for (int q = 0; q < 8; q++) onesu.s[q] = (short)0x3F80;  // bf16 1.0
    const bf16x8 ones = onesu.v;

    bf16x8 stg[4];
#pragma unroll
    for (int k2 = 0; k2 < 4; k2++) stg[k2] = *(const bf16x8*)(srcb + k2 * 64);
    bf16x8 mreg = *(const bf16x8*)(Mrow);

    for (int jt = 0; jt < 4; jt++) {
        __syncthreads();                     // prev compute done; vt free
#pragma unroll
        for (int k2 = 0; k2 < 4; k2++) *(bf16x8*)&vt[srow][scol + k2 * 64] = stg[k2];
        if (jt < 3) {
#pragma unroll
            for (int k2 = 0; k2 < 4; k2++)
                stg[k2] = *(const bf16x8*)(srcb + (jt + 1) * 256 + k2 * 64);
        }
        __syncthreads();

#pragma unroll
        for (int jc = 0; jc < 8; jc++) {
            union { bf16x8 v; unsigned u[4]; } mc;
            mc.v = mreg;
            if (!(jt == 3 && jc == 7))
                mreg = *(const bf16x8*)(Mrow + jt * 256 + jc * 32 + 32);

            const float* f2p = &f2s[jt * 256 + jc * 32 + jb];
            float4 fa = *(const float4*)f2p;
            float4 fb = *(const float4*)(f2p + 4);
            float f2a[8] = {fa.x, fa.y, fa.z, fa.w, fb.x, fb.y, fb.z, fb.w};
            union { bf16x8 v; __hip_bfloat16 hh[8]; } afr;
#pragma unroll
            for (int d = 0; d < 4; d++) {
                float mlo = __uint_as_float(mc.u[d] << 16);
                float mhi = __uint_as_float(mc.u[d] & 0xffff0000u);
                float s0 = f1v + f2a[2 * d] + mlo;       // v_add3
                float s1 = f1v + f2a[2 * d + 1] + mhi;
                s0 = fmaxf(s0, 0.2f * s0);               // LeakyReLU (scale-invariant)
                s1 = fmaxf(s1, 0.2f * s1);
                float p0 = __builtin_amdgcn_exp2f(s0);   // single v_exp_f32
                float p1 = __builtin_amdgcn_exp2f(s1);
                afr.hh[2 * d]     = __float2bfloat16(p0);
                afr.hh[2 * d + 1] = __float2bfloat16(p1);
            }
#pragma unroll
            for (int q = 0; q < 4; q++) {
                bf16x8 bfr = *(const bf16x8*)&vt[q * 16 + li][jc * 32 + jb];
                acc[q] = __builtin_amdgcn_mfma_f32_16x16x32_bf16(afr.v, bfr, acc[q], 0, 0, 0);
            }
            acc5 = __builtin_amdgcn_mfma_f32_16x16x32_bf16(afr.v, ones, acc5, 0, 0, 0);
        }
    }

    float rin[4];
#pragma unroll
    for (int r2 = 0; r2 < 4; r2++) rin[r2] = 1.0f / acc5[r2];

    if (CONCAT) {
        __hip_bfloat16* HCg = HC + (size_t)g * N_NODES * 256 + h * 64;
#pragma unroll
        for (int q = 0; q < 4; q++)
#pragma unroll
            for (int r2 = 0; r2 < 4; r2++) {
                int irow = wv * 16 + grp * 4 + r2;
                float v = acc[q][r2] * rin[r2];
                v = v > 0.f ? v : expm1f(v); // ELU
                HCg[(size_t)(i0 + irow) * 256 + q * 16 + li] = __float2bfloat16(v);
            }
    } else {
        float* og = out + (size_t)g * N_NODES * FDIM;
#pragma unroll
        for (int q = 0; q < 4; q++)
#pragma unroll
            for (int r2 = 0; r2 < 4; r2++) {
                int irow = wv * 16 + grp * 4 + r2;
                float v = acc[q][r2] * rin[r2];
                og[(size_t)(i0 + irow) * FDIM + q * 16 + li] = v > 0.f ? v : 0.f;
            }
    }
}

// ---------------- K3: layer-2 projection + score vectors ----------------
__global__ __launch_bounds__(256) void k_proj2(const __hip_bfloat16* __restrict__ HC,
                                               const float* __restrict__ Wo,
                                               const float* __restrict__ ao,
                                               __hip_bfloat16* __restrict__ H2T,
                                               float* __restrict__ F1b,
                                               float* __restrict__ F2b) {
    __shared__ float xs[64][68];
    __shared__ float ws[64][64];
    const int t = threadIdx.x;
    const int nt = blockIdx.x, g = blockIdx.y;
    const int n0 = nt * 64;
    const int r = t >> 2, cq = t & 3;
    float acc[16];
#pragma unroll
    for (int c = 0; c < 16; c++) acc[c] = 0.f;

    for (int k0 = 0; k0 < 256; k0 += 64) {
        const __hip_bfloat16* src = HC + ((size_t)g * N_NODES + n0 + r) * 256 + k0 + cq * 16;
        union { bf16x8 v; __hip_bfloat16 hh[8]; } u0, u1;
        u0.v = *(const bf16x8*)(src);
        u1.v = *(const bf16x8*)(src + 8);
#pragma unroll
        for (int c = 0; c < 8; c++) {
            xs[r][cq * 16 + c] = __bfloat162float(u0.hh[c]);
            xs[r][cq * 16 + 8 + c] = __bfloat162float(u1.hh[c]);
        }
        const float4* wsrc = (const float4*)(Wo + (size_t)(k0 + r) * 64 + cq * 16);
#pragma unroll
        for (int q = 0; q < 4; q++) *(float4*)&ws[r][cq * 16 + q * 4] = wsrc[q];
        __syncthreads();
        for (int k = 0; k < 64; k++) {
            float a = xs[r][k];
            const float* wr = &ws[k][cq * 16];
#pragma unroll
            for (int c = 0; c < 16; c++) acc[c] = fmaf(a, wr[c], acc[c]);
        }
        __syncthreads();
    }

    float p1 = 0.f, p2 = 0.f;
#pragma unroll
    for (int c = 0; c < 16; c++) {
        p1 = fmaf(acc[c], ao[cq * 16 + c], p1);
        p2 = fmaf(acc[c], ao[64 + cq * 16 + c], p2);
    }
    p1 += __shfl_xor(p1, 1); p1 += __shfl_xor(p1, 2);
    p2 += __shfl_xor(p2, 1); p2 += __shfl_xor(p2, 2);
    const int n = n0 + r;
    if (cq == 0) {
        F1b[(size_t)g * N_NODES + n] = p1 * LOG2E;
        F2b[(size_t)g * N_NODES + n] = p2 * LOG2E;
    }
    __hip_bfloat16* Hb = H2T + (size_t)g * FDIM * N_NODES;
#pragma unroll
    for (int c = 0; c < 16; c++)
        Hb[(size_t)(cq * 16 + c) * N_NODES + n] = __float2bfloat16(acc[c]);
}

extern "C" void kernel_launch(void* const* d_in, const int* in_sizes, int n_in,
                              void* d_out, int out_size, void* d_ws, size_t ws_size,
                              hipStream_t stream) {
    const float* x  = (const float*)d_in[0];
    const int* adj  = (const int*)d_in[1];
    const float* Wh = (const float*)d_in[2];
    const float* ah = (const float*)d_in[3];
    const float* Wo = (const float*)d_in[4];
    const float* ao = (const float*)d_in[5];

    char* ws = (char*)d_ws;
    __hip_bfloat16* Madd = (__hip_bfloat16*)(ws);                  // 2 MB
    float* F1  = (float*)(ws + 2097152);                           // 512 KB
    float* F2  = (float*)(ws + 2621440);                           // 512 KB
    float* F1b = (float*)(ws + 3145728);                           // 128 KB
    float* F2b = (float*)(ws + 3276800);                           // 128 KB
    __hip_bfloat16* H1T = (__hip_bfloat16*)(ws + 3407872);             // 16 MB
    __hip_bfloat16* HC  = (__hip_bfloat16*)(ws + 3407872 + 16777216);  // 16 MB
    __hip_bfloat16* H2T = (__hip_bfloat16*)(ws + 3407872 + 33554432);  //  4 MB
    float* out = (float*)d_out;

    k_maskf  <<<dim3(128),       dim3(256), 0, stream>>>(adj, Madd);
    k_proj1  <<<dim3(16, 32, 4), dim3(256), 0, stream>>>(x, Wh, ah, H1T, F1, F2);
    k_attn<1><<<dim3(8, 32, 4),  dim3(512), 0, stream>>>(H1T, F1, F2, Madd, HC, nullptr);
    k_proj2  <<<dim3(16, 32),    dim3(256), 0, stream>>>(HC, Wo, ao, H2T, F1b, F2b);
    k_attn<0><<<dim3(8, 32, 1),  dim3(512), 0, stream>>>(H2T, F1b, F2b, Madd, nullptr, out);
}